// Round 14
// baseline (1178.437 us; speedup 1.0000x reference)
//
#include <hip/hip_runtime.h>
#include <hip/hip_cooperative_groups.h>

namespace cg = cooperative_groups;

#define N_NODESC 50000
#define N_EDGESC 600000
#define HID 128
#define LAYERS 3
#define N_GRAPHSC 16
#define OUT_DIM 14
#define GEN_EPS 1e-7f
#define BN_EPS 1e-5f
#define LOG2E 1.44269504f

// mega geometry
#define GRID 391         // <=512 blocks: launchable even under 64KB/CU LDS budget
#define BLK 512
#define GSZ (GRID * BLK)
#define NTILES 782       // 64-row tiles covering 50048 rows
#define SCANB 98         // scan: 98 blocks x 512 nodes

// fallback (R12) geometry
#define SCAN_BLK 196
#define POOL_BLK 400
#define EMB_BLK 6250
#define WF_BLK 192
#define GEMM_BLK 782
#define BNR_BLK 64

typedef short bf16x8 __attribute__((ext_vector_type(8)));
typedef float f32x4 __attribute__((ext_vector_type(4)));

__device__ __forceinline__ unsigned short f2bf(float f) {
    union { float f; unsigned u; } v; v.f = f;
    unsigned r = v.u + 0x7FFF + ((v.u >> 16) & 1);  // RNE
    return (unsigned short)(r >> 16);
}
__device__ __forceinline__ float bf_lo(unsigned u) {
    return __uint_as_float(u << 16);
}
__device__ __forceinline__ float bf_hi(unsigned u) {
    return __uint_as_float(u & 0xFFFF0000u);
}
__device__ __forceinline__ float bfs(unsigned short u) {
    return __uint_as_float(((unsigned)u) << 16);
}

// ======================= cooperative megakernel =======================
__global__ __launch_bounds__(512, 4) void k_mega(
    const int* __restrict__ nf0, const int* __restrict__ nf1,
    const int* __restrict__ ef0, const int* __restrict__ ef1,
    const int* __restrict__ esrc, const int* __restrict__ edst,
    const float4* __restrict__ W0, const float4* __restrict__ W1,
    const float* __restrict__ e0all, const float* __restrict__ e1all,
    const float* __restrict__ beta_p, const float* __restrict__ mlpW,
    const float* __restrict__ mlpb, const float* __restrict__ gamma,
    const float* __restrict__ betab, const float* __restrict__ Wo,
    const float* __restrict__ bo, float* __restrict__ out,
    unsigned short* __restrict__ hvb, unsigned* __restrict__ hv1b,
    float* __restrict__ gsums, unsigned short* __restrict__ wfrag,
    int* __restrict__ row_ptr, int* __restrict__ cursor,
    int* __restrict__ deg, int* __restrict__ part, int* __restrict__ bofs,
    int* __restrict__ csr_pack, float* __restrict__ hg,
    int* __restrict__ tctr) {
    cg::grid_group grid = cg::this_grid();
    __shared__ unsigned x_tile[4096];      // 16384 B (scratch reuse in P1/P2/pool)
    __shared__ float2 sh_et[18 * 64];      // 9216 B
    __shared__ float shs[512], shs2[512];  // 4096 B
    __shared__ int s_tile;
    int tid = threadIdx.x, bid = blockIdx.x;
    int gt = bid * BLK + tid;
    const float invN = 1.f / (float)N_NODESC;
    int c4 = tid & 31, rg = tid >> 5;

    // ---- P0: zero deg / counters / gsums / hg ----
    for (int i = gt; i < N_NODESC; i += GSZ) deg[i] = 0;
    if (bid == 0 && tid < 16) tctr[tid] = 0;
    if (bid == 1)
        for (int i = tid; i < LAYERS * 256; i += BLK) gsums[i] = 0.f;
    if (bid == 2)
        for (int i = tid; i < N_GRAPHSC * HID; i += BLK) hg[i] = 0.f;
    grid.sync();

    // ---- P1: degree count + wfrag + embed (2 static tiles, + layer-0 stats) ----
    for (int e = gt; e < N_EDGESC; e += GSZ) atomicAdd(&deg[edst[e]], 1);
    for (int i = gt; i < LAYERS * 16384; i += GSZ) {
        int j = i & 7, lane = (i >> 3) & 63, nt = (i >> 9) & 7;
        int ks = (i >> 12) & 3, l = i >> 14;
        int k = ks * 32 + (lane >> 4) * 8 + j;
        int n = nt * 16 + (lane & 15);
        wfrag[i] = f2bf(mlpW[(size_t)l * HID * HID + k * HID + n]);
    }
    {
        float sacc[4] = {0.f, 0.f, 0.f, 0.f}, qacc[4] = {0.f, 0.f, 0.f, 0.f};
        for (int t = 0; t < 2; t++) {
            int m0 = (bid * 2 + t) * 64;
            for (int it = 0; it < 4; it++) {
                int v = m0 + it * 16 + rg;
                if (v < N_NODESC) {
                    float4 a = W0[nf0[v] * 32 + c4];
                    float4 b = W1[nf1[v] * 32 + c4];
                    float o[4] = {a.x + b.x, a.y + b.y, a.z + b.z, a.w + b.w};
                    uint2 ob;
                    ob.x = (unsigned)f2bf(o[0]) | ((unsigned)f2bf(o[1]) << 16);
                    ob.y = (unsigned)f2bf(o[2]) | ((unsigned)f2bf(o[3]) << 16);
                    ((uint2*)hvb)[(size_t)v * 32 + c4] = ob;
#pragma unroll
                    for (int j = 0; j < 4; j++) {
                        sacc[j] += o[j];
                        qacc[j] += o[j] * o[j];
                    }
                }
            }
        }
        float* sA = (float*)x_tile;
        float* sB = sA + 2048;
#pragma unroll
        for (int j = 0; j < 4; j++) {
            sA[rg * 128 + c4 * 4 + j] = sacc[j];
            sB[rg * 128 + c4 * 4 + j] = qacc[j];
        }
        __syncthreads();
        if (tid < 128) {
            float s = 0.f, q = 0.f;
#pragma unroll
            for (int r = 0; r < 16; r++) {
                s += sA[r * 128 + tid];
                q += sB[r * 128 + tid];
            }
            atomicAdd(&gsums[tid], s);
            atomicAdd(&gsums[128 + tid], q);
        }
    }
    grid.sync();

    // ---- P2: per-block degree sums (blocks 0..97) ----
    if (bid < SCANB) {
        int i = bid * BLK + tid;
        int d = (i < N_NODESC) ? deg[i] : 0;
        int* shi = (int*)x_tile;
        shi[tid] = d;
        __syncthreads();
        for (int off = 256; off > 0; off >>= 1) {
            if (tid < off) shi[tid] += shi[tid + off];
            __syncthreads();
        }
        if (tid == 0) part[bid] = shi[0];
    }
    grid.sync();
    // ---- P3: exclusive scan of 98 partials (block 0) ----
    if (bid == 0) {
        int* shi = (int*)x_tile;
        int v = (tid < SCANB) ? part[tid] : 0;
        if (tid < 128) shi[tid] = v;
        __syncthreads();
        for (int off = 1; off < 128; off <<= 1) {
            int add = (tid >= off && tid < 128) ? shi[tid - off] : 0;
            __syncthreads();
            if (tid < 128) shi[tid] += add;
            __syncthreads();
        }
        if (tid < SCANB) bofs[tid] = shi[tid] - v;
    }
    grid.sync();
    // ---- P4: row_ptr / cursor (blocks 0..97) ----
    if (bid < SCANB) {
        int i = bid * BLK + tid;
        int d = (i < N_NODESC) ? deg[i] : 0;
        int* shi = (int*)x_tile;
        shi[tid] = d;
        __syncthreads();
        for (int off = 1; off < 512; off <<= 1) {
            int add = (tid >= off) ? shi[tid - off] : 0;
            __syncthreads();
            shi[tid] += add;
            __syncthreads();
        }
        if (i < N_NODESC) {
            int rp = bofs[bid] + shi[tid] - d;
            row_ptr[i] = rp;
            cursor[i] = rp;
        }
        if (i == 0) row_ptr[N_NODESC] = N_EDGESC;
    }
    grid.sync();
    // ---- P5: scatter (pack = (src<<8) | f01*8) ----
    for (int e = gt; e < N_EDGESC; e += GSZ) {
        int pos = atomicAdd(&cursor[edst[e]], 1);
        csr_pack[pos] = (esrc[e] << 8) | ((ef0[e] * 3 + ef1[e]) * 8);
    }
    grid.sync();

    // ---- layers ----
    int w = tid >> 6, lane = tid & 63;
    const char* hv1c = (const char*)hv1b;
    const char* etc = (const char*)sh_et;
    unsigned lane4 = (unsigned)lane * 4;
    unsigned lane8 = (unsigned)lane * 8;
    for (int l = 0; l < LAYERS; l++) {
        const float* gsum = gsums + l * 256;
        // BN+ReLU -> hv1b (2 static tiles)
        {
            int c = c4 * 4;
            float sc[4], sf[4];
#pragma unroll
            for (int j = 0; j < 4; j++) {
                float mu = gsum[c + j] * invN;
                float var = gsum[128 + c + j] * invN - mu * mu;
                float s = gamma[l * HID + c + j] * rsqrtf(var + BN_EPS);
                sc[j] = s;
                sf[j] = betab[l * HID + c + j] - mu * s;
            }
            for (int t = 0; t < 2; t++) {
                int m0 = (bid * 2 + t) * 64;
                for (int it = 0; it < 4; it++) {
                    int v = m0 + it * 16 + rg;
                    if (v < N_NODESC) {
                        uint2 hb = ((const uint2*)hvb)[(size_t)v * 32 + c4];
                        float h[4] = {bf_lo(hb.x), bf_hi(hb.x),
                                      bf_lo(hb.y), bf_hi(hb.y)};
                        float r[4];
#pragma unroll
                        for (int j = 0; j < 4; j++)
                            r[j] = fmaxf(fmaf(h[j], sc[j], sf[j]), 0.f);
                        uint2 o;
                        o.x = (unsigned)f2bf(r[0]) | ((unsigned)f2bf(r[1]) << 16);
                        o.y = (unsigned)f2bf(r[2]) | ((unsigned)f2bf(r[3]) << 16);
                        ((uint2*)hv1b)[(size_t)v * 32 + c4] = o;
                    }
                }
            }
        }
        grid.sync();

        // fill per-layer edge table
        const float* e0 = e0all + (size_t)l * 6 * HID;
        const float* e1 = e1all + (size_t)l * 3 * HID;
        const unsigned short* wf = wfrag + (size_t)l * 16384;
        for (int i = tid; i < 18 * 64; i += BLK) {
            int f = i >> 6, ln = i & 63;
            int a = f / 3, bb = f - 3 * a;
            float2 ea = *(const float2*)(e0 + a * HID + 2 * ln);
            float2 eb = *(const float2*)(e1 + bb * HID + 2 * ln);
            sh_et[i] = make_float2(ea.x + eb.x, ea.y + eb.y);
        }
        float bl2 = beta_p[l] * LOG2E;
        __syncthreads();

#define AGG_BODY(J)                                                         \
    {                                                                       \
        int pack = __shfl(pk, (J), 64);                                     \
        unsigned u = *(const unsigned*)(hv1c +                              \
                        ((((unsigned)pack) & 0xFFFFFF00u) + lane4));        \
        float2 t = *(const float2*)(etc +                                   \
                        (((((unsigned)pack) & 0xFFu) << 6) + lane8));       \
        float r0 = fmaxf(bf_lo(u) + t.x, 0.f);                              \
        float r1 = fmaxf(bf_hi(u) + t.y, 0.f);                              \
        float w0 = exp2f(r0 * bl2);                                         \
        float w1 = exp2f(r1 * bl2);                                         \
        d0 += w0; d1 += w1;                                                 \
        n0 = fmaf(r0, w0, n0); n1 = fmaf(r1, w1, n1);                       \
    }

        // work-stealing over 782 tiles: balances load across uneven block->CU
        for (;;) {
            if (tid == 0) s_tile = atomicAdd(&tctr[l], 1);
            __syncthreads();
            int tile = s_tile;
            if (tile >= NTILES) break;
            int m0 = tile * 64;
            // phase A: aggregation, 8 rows per wave
            for (int i = 0; i < 8; i++) {
                int row = w * 8 + i;
                int v = m0 + row;
                int vc = min(v, N_NODESC - 1);
                unsigned su = hv1b[(size_t)vc * 64 + lane];
                int p0 = row_ptr[vc];
                int dg = (v < N_NODESC) ? (row_ptr[vc + 1] - p0) : 0;
                float n0 = 0.f, n1 = 0.f, d0 = 0.f, d1 = 0.f;
                for (int base = 0; base < dg; base += 64) {
                    int idx = base + lane;
                    int pk = (idx < dg) ? csr_pack[p0 + idx] : 0;
                    int jn = min(64, dg - base);
                    int j = 0;
                    for (; j + 2 <= jn; j += 2) {
                        AGG_BODY(j)
                        AGG_BODY(j + 1)
                    }
                    if (j < jn) AGG_BODY(j)
                }
                float ox = bf_lo(su) + (dg ? __fdividef(n0, d0) + GEN_EPS : 0.f);
                float oy = bf_hi(su) + (dg ? __fdividef(n1, d1) + GEN_EPS : 0.f);
                x_tile[row * 64 + ((lane + row * 4) & 63)] =
                    (unsigned)f2bf(ox) | ((unsigned)f2bf(oy) << 16);
            }
            __syncthreads();
            // phase B: MFMA + epilogue
            int rw = w & 3, chh = w >> 2;
            int mrow = lane & 15, grp = lane >> 4;
            int rbase = rw * 16 + mrow;
            bf16x8 af[4];
#pragma unroll
            for (int ks = 0; ks < 4; ks++) {
                int col = ks * 16 + grp * 4;
                int colr = (col + rbase * 4) & 63;
                af[ks] = *(const bf16x8*)&x_tile[rbase * 64 + colr];
            }
            f32x4 acc[4];
#pragma unroll
            for (int nt = 0; nt < 4; nt++) acc[nt] = (f32x4){0.f, 0.f, 0.f, 0.f};
#pragma unroll
            for (int nt = 0; nt < 4; nt++) {
                int ntg = chh * 4 + nt;
#pragma unroll
                for (int ks = 0; ks < 4; ks++) {
                    bf16x8 bfr = *(const bf16x8*)(wf +
                        (size_t)((ks * 8 + ntg) * 64 + lane) * 8);
                    acc[nt] = __builtin_amdgcn_mfma_f32_16x16x32_bf16(
                        af[ks], bfr, acc[nt], 0, 0, 0);
                }
            }
#pragma unroll
            for (int nt = 0; nt < 4; nt++) {
                int col = chh * 64 + nt * 16 + mrow;
                float bias = mlpb[l * HID + col];
                float s = 0.f, s2 = 0.f;
#pragma unroll
                for (int r = 0; r < 4; r++) {
                    int v = m0 + rw * 16 + grp * 4 + r;
                    if (v < N_NODESC) {
                        size_t idx = (size_t)v * HID + col;
                        float o = acc[nt][r] + bias + bfs(hvb[idx]);
                        hvb[idx] = f2bf(o);
                        s += o; s2 += o * o;
                    }
                }
                s  += __shfl_xor(s, 16, 64);  s  += __shfl_xor(s, 32, 64);
                s2 += __shfl_xor(s2, 16, 64); s2 += __shfl_xor(s2, 32, 64);
                if (lane < 16) { shs[rw * 128 + col] = s; shs2[rw * 128 + col] = s2; }
            }
            __syncthreads();
            if (l + 1 < LAYERS) {
                float* gn = gsums + (l + 1) * 256;
                if (tid < 128) {
                    atomicAdd(&gn[tid], shs[tid] + shs[128 + tid] +
                                        shs[256 + tid] + shs[384 + tid]);
                } else if (tid < 256) {
                    int c = tid - 128;
                    atomicAdd(&gn[tid], shs2[c] + shs2[128 + c] +
                                        shs2[256 + c] + shs2[384 + c]);
                }
            }
        }
#undef AGG_BODY
        grid.sync();
    }

    // ---- pooling (2 static tiles; at most 2 graphs per tile) ----
    for (int t = 0; t < 2; t++) {
        int m0 = (bid * 2 + t) * 64;
        int gA = m0 / 3125;
        int gB = min(m0 + 63, N_NODESC - 1) / 3125;
        float accA[4] = {0.f, 0.f, 0.f, 0.f}, accB[4] = {0.f, 0.f, 0.f, 0.f};
        for (int it = 0; it < 4; it++) {
            int v = m0 + it * 16 + rg;
            if (v < N_NODESC) {
                uint2 hb = ((const uint2*)hvb)[(size_t)v * 32 + c4];
                float h[4] = {bf_lo(hb.x), bf_hi(hb.x), bf_lo(hb.y), bf_hi(hb.y)};
                if (v / 3125 == gA) {
#pragma unroll
                    for (int j = 0; j < 4; j++) accA[j] += h[j];
                } else {
#pragma unroll
                    for (int j = 0; j < 4; j++) accB[j] += h[j];
                }
            }
        }
        float* sA = (float*)x_tile;
        float* sB = sA + 2048;
        __syncthreads();
#pragma unroll
        for (int j = 0; j < 4; j++) {
            sA[rg * 128 + c4 * 4 + j] = accA[j];
            sB[rg * 128 + c4 * 4 + j] = accB[j];
        }
        __syncthreads();
        if (tid < 128) {
            float s = 0.f;
#pragma unroll
            for (int r = 0; r < 16; r++) s += sA[r * 128 + tid];
            atomicAdd(&hg[gA * 128 + tid], s);
        } else if (tid < 256 && gB != gA) {
            int c = tid - 128;
            float s = 0.f;
#pragma unroll
            for (int r = 0; r < 16; r++) s += sB[r * 128 + c];
            atomicAdd(&hg[gB * 128 + c], s);
        }
        __syncthreads();
    }
    grid.sync();
    // ---- output linear (block 0) ----
    if (bid == 0 && tid < N_GRAPHSC * OUT_DIM) {
        int g = tid / OUT_DIM, o = tid % OUT_DIM;
        const float inv = (float)N_GRAPHSC / (float)N_NODESC;
        float acc = bo[o];
        for (int k = 0; k < HID; k++)
            acc += hg[g * HID + k] * inv * Wo[k * OUT_DIM + o];
        out[tid] = acc;
    }
}

// ======================= fallback (R12) kernels =======================
__global__ void k_count(const int* __restrict__ dst, int* __restrict__ deg) {
    int i = blockIdx.x * blockDim.x + threadIdx.x;
    if (i < N_EDGESC) atomicAdd(&deg[dst[i]], 1);
}

__global__ void k_blocksum(const int* __restrict__ deg, int* __restrict__ part) {
    __shared__ int sh[256];
    int t = threadIdx.x;
    int i = blockIdx.x * 256 + t;
    sh[t] = (i < N_NODESC) ? deg[i] : 0;
    __syncthreads();
    for (int off = 128; off > 0; off >>= 1) {
        if (t < off) sh[t] += sh[t + off];
        __syncthreads();
    }
    if (t == 0) part[blockIdx.x] = sh[0];
}

__global__ void k_scanpart(const int* __restrict__ part, int* __restrict__ bofs) {
    __shared__ int sh[256];
    int t = threadIdx.x;
    int v = (t < SCAN_BLK) ? part[t] : 0;
    sh[t] = v;
    __syncthreads();
    for (int off = 1; off < 256; off <<= 1) {
        int add = (t >= off) ? sh[t - off] : 0;
        __syncthreads();
        sh[t] += add;
        __syncthreads();
    }
    if (t < SCAN_BLK) bofs[t] = sh[t] - v;
}

__global__ void k_rowptr(const int* __restrict__ deg, const int* __restrict__ bofs,
                         int* __restrict__ row_ptr, int* __restrict__ cursor) {
    __shared__ int sh[256];
    int t = threadIdx.x;
    int i = blockIdx.x * 256 + t;
    int d = (i < N_NODESC) ? deg[i] : 0;
    sh[t] = d;
    __syncthreads();
    for (int off = 1; off < 256; off <<= 1) {
        int add = (t >= off) ? sh[t - off] : 0;
        __syncthreads();
        sh[t] += add;
        __syncthreads();
    }
    if (i < N_NODESC) {
        int rp = bofs[blockIdx.x] + sh[t] - d;
        row_ptr[i] = rp;
        cursor[i] = rp;
    }
    if (i == 0) row_ptr[N_NODESC] = N_EDGESC;
}

__global__ void k_scatter(const int* __restrict__ dst, const int* __restrict__ src,
                          const int* __restrict__ f0, const int* __restrict__ f1,
                          int* __restrict__ cursor, int* __restrict__ csr_pack) {
    int i = blockIdx.x * blockDim.x + threadIdx.x;
    if (i < N_EDGESC) {
        int pos = atomicAdd(&cursor[dst[i]], 1);
        csr_pack[pos] = (src[i] << 8) | ((f0[i] * 3 + f1[i]) * 8);
    }
}

__global__ void k_embed(const int* __restrict__ f0, const int* __restrict__ f1,
                        const float4* __restrict__ W0, const float4* __restrict__ W1,
                        uint2* __restrict__ hvb2, float* __restrict__ part,
                        const float* __restrict__ W, unsigned short* __restrict__ wf) {
    int tid = threadIdx.x;
    if (blockIdx.x >= EMB_BLK) {
        int i = (blockIdx.x - EMB_BLK) * 256 + tid;
        if (i < LAYERS * 4 * 8 * 64 * 8) {
            int j = i & 7;
            int lane = (i >> 3) & 63;
            int nt = (i >> 9) & 7;
            int ks = (i >> 12) & 3;
            int l = i >> 14;
            int k = ks * 32 + (lane >> 4) * 8 + j;
            int n = nt * 16 + (lane & 15);
            wf[i] = f2bf(W[(size_t)l * HID * HID + k * HID + n]);
        }
        return;
    }
    __shared__ float sh[1024], sh2[1024];
    int i = blockIdx.x * 256 + tid;
    int v = i >> 5, c4 = i & 31;
    float4 a = W0[f0[v] * 32 + c4];
    float4 b = W1[f1[v] * 32 + c4];
    float4 o = make_float4(a.x + b.x, a.y + b.y, a.z + b.z, a.w + b.w);
    uint2 ob;
    ob.x = (unsigned)f2bf(o.x) | ((unsigned)f2bf(o.y) << 16);
    ob.y = (unsigned)f2bf(o.z) | ((unsigned)f2bf(o.w) << 16);
    hvb2[i] = ob;
    sh[tid * 4 + 0] = o.x; sh2[tid * 4 + 0] = o.x * o.x;
    sh[tid * 4 + 1] = o.y; sh2[tid * 4 + 1] = o.y * o.y;
    sh[tid * 4 + 2] = o.z; sh2[tid * 4 + 2] = o.z * o.z;
    sh[tid * 4 + 3] = o.w; sh2[tid * 4 + 3] = o.w * o.w;
    __syncthreads();
    if (tid < 128) {
        int c4i = tid >> 2, j = tid & 3;
        float s = 0.f, s2 = 0.f;
#pragma unroll
        for (int r = 0; r < 8; r++) {
            s += sh[(r * 32 + c4i) * 4 + j];
            s2 += sh2[(r * 32 + c4i) * 4 + j];
        }
        part[(size_t)blockIdx.x * 256 + tid] = s;
        part[(size_t)blockIdx.x * 256 + 128 + tid] = s2;
    }
}

__global__ void k_bn_reduce2(const float* __restrict__ part, int nparts,
                             float* __restrict__ gsum) {
    int t = threadIdx.x;
    int rows = (nparts + BNR_BLK - 1) / BNR_BLK;
    int r0 = blockIdx.x * rows;
    int r1 = min(r0 + rows, nparts);
    float s = 0.f;
    for (int p = r0; p < r1; p++) s += part[(size_t)p * 256 + t];
    atomicAdd(&gsum[t], s);
}

__global__ void k_hv1b(const uint2* __restrict__ hvb2, const float* __restrict__ gsum,
                       const float* __restrict__ gamma, const float* __restrict__ betab,
                       uint2* __restrict__ hv1b) {
    int i = blockIdx.x * 256 + threadIdx.x;
    int c = (i & 31) * 4;
    const float invN = 1.f / (float)N_NODESC;
    uint2 hb = hvb2[i];
    float h[4] = {bf_lo(hb.x), bf_hi(hb.x), bf_lo(hb.y), bf_hi(hb.y)};
    float r[4];
#pragma unroll
    for (int j = 0; j < 4; j++) {
        float mu = gsum[c + j] * invN;
        float var = gsum[128 + c + j] * invN - mu * mu;
        float sc = gamma[c + j] * rsqrtf(var + BN_EPS);
        float sf = betab[c + j] - mu * sc;
        r[j] = fmaxf(fmaf(h[j], sc, sf), 0.f);
    }
    uint2 o;
    o.x = (unsigned)f2bf(r[0]) | ((unsigned)f2bf(r[1]) << 16);
    o.y = (unsigned)f2bf(r[2]) | ((unsigned)f2bf(r[3]) << 16);
    hv1b[i] = o;
}

__global__ __launch_bounds__(512) void k_aggemm(
    const unsigned* __restrict__ hv1b, const int* __restrict__ row_ptr,
    const int* __restrict__ csr_pack, const float* __restrict__ e0,
    const float* __restrict__ e1, const float* __restrict__ beta_p,
    const unsigned short* __restrict__ wf, const float* __restrict__ b,
    unsigned short* __restrict__ hvb, float* __restrict__ gsum_next) {
    __shared__ float2 sh_et[18 * 64];
    __shared__ unsigned x_tile[64 * 64];
    __shared__ float shs[512], shs2[512];
    int tid = threadIdx.x;
    for (int i = tid; i < 18 * 64; i += 512) {
        int f = i >> 6, ln = i & 63;
        int a = f / 3, bb = f - 3 * a;
        float2 ea = *(const float2*)(e0 + a * HID + 2 * ln);
        float2 eb = *(const float2*)(e1 + bb * HID + 2 * ln);
        sh_et[i] = make_float2(ea.x + eb.x, ea.y + eb.y);
    }
    int w = tid >> 6, lane = tid & 63;
    int m0 = blockIdx.x * 64;
    float beta = *beta_p;
    const float bl2 = beta * LOG2E;
    __syncthreads();

    const char* hv1c = (const char*)hv1b;
    const char* etc = (const char*)sh_et;
    unsigned lane4 = (unsigned)lane * 4;
    unsigned lane8 = (unsigned)lane * 8;

#define AGG_BODY(J)                                                         \
    {                                                                       \
        int pack = __shfl(pk, (J), 64);                                     \
        unsigned u = *(const unsigned*)(hv1c +                              \
                        ((((unsigned)pack) & 0xFFFFFF00u) + lane4));        \
        float2 t = *(const float2*)(etc +                                   \
                        (((((unsigned)pack) & 0xFFu) << 6) + lane8));       \
        float r0 = fmaxf(bf_lo(u) + t.x, 0.f);                              \
        float r1 = fmaxf(bf_hi(u) + t.y, 0.f);                              \
        float w0 = exp2f(r0 * bl2);                                         \
        float w1 = exp2f(r1 * bl2);                                         \
        d0 += w0; d1 += w1;                                                 \
        n0 = fmaf(r0, w0, n0); n1 = fmaf(r1, w1, n1);                       \
    }

    for (int i = 0; i < 8; i++) {
        int row = w * 8 + i;
        int v = m0 + row;
        int vc = min(v, N_NODESC - 1);
        unsigned su = hv1b[(size_t)vc * 64 + lane];
        int p0 = row_ptr[vc];
        int deg = (v < N_NODESC) ? (row_ptr[vc + 1] - p0) : 0;
        float n0 = 0.f, n1 = 0.f, d0 = 0.f, d1 = 0.f;
        for (int base = 0; base < deg; base += 64) {
            int idx = base + lane;
            int pk = (idx < deg) ? csr_pack[p0 + idx] : 0;
            int jn = min(64, deg - base);
            int j = 0;
            for (; j + 2 <= jn; j += 2) {
                AGG_BODY(j)
                AGG_BODY(j + 1)
            }
            if (j < jn) AGG_BODY(j)
        }
        float ox = bf_lo(su) + (deg ? __fdividef(n0, d0) + GEN_EPS : 0.f);
        float oy = bf_hi(su) + (deg ? __fdividef(n1, d1) + GEN_EPS : 0.f);
        x_tile[row * 64 + ((lane + row * 4) & 63)] =
            (unsigned)f2bf(ox) | ((unsigned)f2bf(oy) << 16);
    }
#undef AGG_BODY
    __syncthreads();

    int rw = w & 3, chh = w >> 2;
    int mrow = lane & 15, grp = lane >> 4;
    int rbase = rw * 16 + mrow;
    bf16x8 af[4];
#pragma unroll
    for (int ks = 0; ks < 4; ks++) {
        int col = ks * 16 + grp * 4;
        int colr = (col + rbase * 4) & 63;
        af[ks] = *(const bf16x8*)&x_tile[rbase * 64 + colr];
    }
    f32x4 acc[4];
#pragma unroll
    for (int nt = 0; nt < 4; nt++) acc[nt] = (f32x4){0.f, 0.f, 0.f, 0.f};
#pragma unroll
    for (int nt = 0; nt < 4; nt++) {
        int ntg = chh * 4 + nt;
#pragma unroll
        for (int ks = 0; ks < 4; ks++) {
            bf16x8 bfr = *(const bf16x8*)(wf +
                (size_t)((ks * 8 + ntg) * 64 + lane) * 8);
            acc[nt] = __builtin_amdgcn_mfma_f32_16x16x32_bf16(
                af[ks], bfr, acc[nt], 0, 0, 0);
        }
    }
#pragma unroll
    for (int nt = 0; nt < 4; nt++) {
        int col = chh * 64 + nt * 16 + mrow;
        float bias = b[col];
        float s = 0.f, s2 = 0.f;
#pragma unroll
        for (int r = 0; r < 4; r++) {
            int v = m0 + rw * 16 + grp * 4 + r;
            if (v < N_NODESC) {
                size_t idx = (size_t)v * HID + col;
                float o = acc[nt][r] + bias + bfs(hvb[idx]);
                hvb[idx] = f2bf(o);
                s += o; s2 += o * o;
            }
        }
        s  += __shfl_xor(s, 16, 64);  s  += __shfl_xor(s, 32, 64);
        s2 += __shfl_xor(s2, 16, 64); s2 += __shfl_xor(s2, 32, 64);
        if (lane < 16) { shs[rw * 128 + col] = s; shs2[rw * 128 + col] = s2; }
    }
    if (gsum_next) {
        __syncthreads();
        if (tid < 128) {
            atomicAdd(&gsum_next[tid],
                shs[tid] + shs[128 + tid] + shs[256 + tid] + shs[384 + tid]);
        } else if (tid < 256) {
            int c = tid - 128;
            atomicAdd(&gsum_next[tid],
                shs2[c] + shs2[128 + c] + shs2[256 + c] + shs2[384 + c]);
        }
    }
}

__global__ void k_pool(const unsigned short* __restrict__ hvb,
                       float* __restrict__ part2) {
    int tid = threadIdx.x;
    int c = tid & 127, rh = tid >> 7;
    int start = blockIdx.x * 125;
    float acc = 0.f;
    for (int r = start + rh; r < start + 125; r += 2)
        acc += bfs(hvb[(size_t)r * HID + c]);
    __shared__ float sh[256];
    sh[tid] = acc;
    __syncthreads();
    if (rh == 0) part2[blockIdx.x * 128 + c] = acc + sh[tid + 128];
}

__global__ void k_finish(const float* __restrict__ part2, const float* __restrict__ Wo,
                         const float* __restrict__ bo, float* __restrict__ out) {
    __shared__ float hg[N_GRAPHSC * HID];
    int t = threadIdx.x;
    for (int s = t; s < N_GRAPHSC * HID; s += 256) {
        int g = s >> 7, c = s & 127;
        float x = 0.f;
#pragma unroll
        for (int i = 0; i < 25; i++) x += part2[(g * 25 + i) * 128 + c];
        hg[s] = x;
    }
    __syncthreads();
    if (t < N_GRAPHSC * OUT_DIM) {
        int g = t / OUT_DIM, o = t % OUT_DIM;
        const float inv = (float)N_GRAPHSC / (float)N_NODESC;
        float acc = bo[o];
        for (int k = 0; k < HID; k++)
            acc += hg[g * HID + k] * inv * Wo[k * OUT_DIM + o];
        out[t] = acc;
    }
}

extern "C" void kernel_launch(void* const* d_in, const int* in_sizes, int n_in,
                              void* d_out, int out_size, void* d_ws, size_t ws_size,
                              hipStream_t stream) {
    const int* node_feat0 = (const int*)d_in[0];
    const int* node_feat1 = (const int*)d_in[1];
    const int* edge_feat0 = (const int*)d_in[2];
    const int* edge_feat1 = (const int*)d_in[3];
    const int* edge_src   = (const int*)d_in[4];
    const int* edge_dst   = (const int*)d_in[5];
    const float* W_node0   = (const float*)d_in[8];
    const float* W_node1   = (const float*)d_in[9];
    const float* edge_emb0 = (const float*)d_in[10];
    const float* edge_emb1 = (const float*)d_in[11];
    const float* beta      = (const float*)d_in[12];
    const float* mlp_W     = (const float*)d_in[13];
    const float* mlp_b     = (const float*)d_in[14];
    const float* bn_gamma  = (const float*)d_in[15];
    const float* bn_beta   = (const float*)d_in[16];
    const float* W_out     = (const float*)d_in[17];
    const float* b_out     = (const float*)d_in[18];
    float* out = (float*)d_out;

    char* ws = (char*)d_ws;
    size_t off = 0;
    auto alloc = [&](size_t bytes) -> void* {
        void* p = ws + off;
        off += (bytes + 255) & ~(size_t)255;
        return p;
    };
    unsigned short* hvb = (unsigned short*)alloc((size_t)N_NODESC * HID * 2);
    unsigned* hv1b = (unsigned*)alloc((size_t)N_NODESC * 64 * 4);
    float* gsums   = (float*)alloc(LAYERS * 256 * 4);
    unsigned short* wfrag = (unsigned short*)alloc((size_t)LAYERS * 16384 * 2);
    int* row_ptr   = (int*)alloc((N_NODESC + 1) * 4);
    int* cursor    = (int*)alloc(N_NODESC * 4);
    int* deg       = (int*)alloc(N_NODESC * 4);
    int* part      = (int*)alloc(256 * 4);
    int* bofs      = (int*)alloc(256 * 4);
    int* csr_pack  = (int*)alloc((size_t)N_EDGESC * 4);
    float* hg      = (float*)alloc(N_GRAPHSC * HID * 4);
    int* tctr      = (int*)alloc(64 * 4);
    float* bnpart  = (float*)alloc((size_t)EMB_BLK * 256 * 4);   // fallback only
    float* part2   = (float*)alloc(POOL_BLK * 128 * 4);          // fallback only

    void* args[] = {
        (void*)&node_feat0, (void*)&node_feat1,
        (void*)&edge_feat0, (void*)&edge_feat1,
        (void*)&edge_src, (void*)&edge_dst,
        (void*)&W_node0, (void*)&W_node1,
        (void*)&edge_emb0, (void*)&edge_emb1,
        (void*)&beta, (void*)&mlp_W, (void*)&mlp_b,
        (void*)&bn_gamma, (void*)&bn_beta,
        (void*)&W_out, (void*)&b_out, (void*)&out,
        (void*)&hvb, (void*)&hv1b, (void*)&gsums, (void*)&wfrag,
        (void*)&row_ptr, (void*)&cursor, (void*)&deg,
        (void*)&part, (void*)&bofs, (void*)&csr_pack, (void*)&hg,
        (void*)&tctr,
    };
    hipError_t err = hipLaunchCooperativeKernel(
        (const void*)k_mega, dim3(GRID), dim3(BLK), args, 0, stream);
    if (err == hipSuccess) return;

    // -------- fallback: proven R12 multi-kernel path --------
    hipMemsetAsync(deg, 0, N_NODESC * 4, stream);
    hipMemsetAsync(gsums, 0, LAYERS * 256 * 4, stream);
    k_count<<<(N_EDGESC + 255) / 256, 256, 0, stream>>>(edge_dst, deg);
    k_blocksum<<<SCAN_BLK, 256, 0, stream>>>(deg, part);
    k_scanpart<<<1, 256, 0, stream>>>(part, bofs);
    k_rowptr<<<SCAN_BLK, 256, 0, stream>>>(deg, bofs, row_ptr, cursor);
    k_scatter<<<(N_EDGESC + 255) / 256, 256, 0, stream>>>(
        edge_dst, edge_src, edge_feat0, edge_feat1, cursor, csr_pack);
    k_embed<<<EMB_BLK + WF_BLK, 256, 0, stream>>>(
        node_feat0, node_feat1, (const float4*)W_node0, (const float4*)W_node1,
        (uint2*)hvb, bnpart, mlp_W, wfrag);
    k_bn_reduce2<<<BNR_BLK, 256, 0, stream>>>(bnpart, EMB_BLK, gsums);
    for (int l = 0; l < LAYERS; l++) {
        float* gsum = gsums + l * 256;
        float* gnext = (l + 1 < LAYERS) ? gsums + (l + 1) * 256 : nullptr;
        k_hv1b<<<(N_NODESC * 32) / 256, 256, 0, stream>>>(
            (const uint2*)hvb, gsum, bn_gamma + l * HID, bn_beta + l * HID,
            (uint2*)hv1b);
        k_aggemm<<<GEMM_BLK, 512, 0, stream>>>(
            hv1b, row_ptr, csr_pack,
            edge_emb0 + (size_t)l * 6 * HID, edge_emb1 + (size_t)l * 3 * HID,
            beta + l, wfrag + (size_t)l * 16384, mlp_b + l * HID, hvb, gnext);
    }
    k_pool<<<POOL_BLK, 256, 0, stream>>>(hvb, part2);
    k_finish<<<1, 256, 0, stream>>>(part2, W_out, b_out, out);
}

// Round 15
// 422.384 us; speedup vs baseline: 2.7900x; 2.7900x over previous
//
#include <hip/hip_runtime.h>

#define N_NODESC 50000
#define N_EDGESC 600000
#define HID 128
#define LAYERS 3
#define N_GRAPHSC 16
#define OUT_DIM 14
#define GEN_EPS 1e-7f
#define BN_EPS 1e-5f
#define SCAN_BLK 196     // ceil(50000/256)
#define EMB_BLK 6250     // embed blocks (8 rows each)
#define WF_BLK 192       // wfrag tail blocks
#define CNT_BLK 2344     // degree-count tail blocks (600000/256)
#define GEMM_BLK 782     // ceil(50000/64)
#define BNR_BLK 64       // bn reduce blocks (layer 0 only)
#define LOG2E 1.44269504f

typedef short bf16x8 __attribute__((ext_vector_type(8)));
typedef float f32x4 __attribute__((ext_vector_type(4)));

__device__ __forceinline__ unsigned short f2bf(float f) {
    union { float f; unsigned u; } v; v.f = f;
    unsigned r = v.u + 0x7FFF + ((v.u >> 16) & 1);  // RNE
    return (unsigned short)(r >> 16);
}
__device__ __forceinline__ float bf_lo(unsigned u) {
    return __uint_as_float(u << 16);
}
__device__ __forceinline__ float bf_hi(unsigned u) {
    return __uint_as_float(u & 0xFFFF0000u);
}
__device__ __forceinline__ float bfs(unsigned short u) {
    return __uint_as_float(((unsigned)u) << 16);
}

// ---------------- CSR build ----------------
__global__ void k_blocksum(const int* __restrict__ deg, int* __restrict__ part) {
    __shared__ int sh[256];
    int t = threadIdx.x;
    int i = blockIdx.x * 256 + t;
    sh[t] = (i < N_NODESC) ? deg[i] : 0;
    __syncthreads();
    for (int off = 128; off > 0; off >>= 1) {
        if (t < off) sh[t] += sh[t + off];
        __syncthreads();
    }
    if (t == 0) part[blockIdx.x] = sh[0];
}

__global__ void k_scanpart(const int* __restrict__ part, int* __restrict__ bofs) {
    __shared__ int sh[256];
    int t = threadIdx.x;
    int v = (t < SCAN_BLK) ? part[t] : 0;
    sh[t] = v;
    __syncthreads();
    for (int off = 1; off < 256; off <<= 1) {
        int add = (t >= off) ? sh[t - off] : 0;
        __syncthreads();
        sh[t] += add;
        __syncthreads();
    }
    if (t < SCAN_BLK) bofs[t] = sh[t] - v;  // exclusive
}

__global__ void k_rowptr(const int* __restrict__ deg, const int* __restrict__ bofs,
                         int* __restrict__ row_ptr, int* __restrict__ cursor) {
    __shared__ int sh[256];
    int t = threadIdx.x;
    int i = blockIdx.x * 256 + t;
    int d = (i < N_NODESC) ? deg[i] : 0;
    sh[t] = d;
    __syncthreads();
    for (int off = 1; off < 256; off <<= 1) {
        int add = (t >= off) ? sh[t - off] : 0;
        __syncthreads();
        sh[t] += add;
        __syncthreads();
    }
    if (i < N_NODESC) {
        int rp = bofs[blockIdx.x] + sh[t] - d;
        row_ptr[i] = rp;
        cursor[i] = rp;
    }
    if (i == 0) row_ptr[N_NODESC] = N_EDGESC;
}

// pack = (src<<8) | f01*8
__global__ void k_scatter(const int* __restrict__ dst, const int* __restrict__ src,
                          const int* __restrict__ f0, const int* __restrict__ f1,
                          int* __restrict__ cursor, int* __restrict__ csr_pack) {
    int i = blockIdx.x * blockDim.x + threadIdx.x;
    if (i < N_EDGESC) {
        int pos = atomicAdd(&cursor[dst[i]], 1);
        csr_pack[pos] = (src[i] << 8) | ((f0[i] * 3 + f1[i]) * 8);
    }
}

// ---------------- embed (+layer-0 BN partials) + wfrag tail + count tail ----
__global__ void k_embed(const int* __restrict__ f0, const int* __restrict__ f1,
                        const float4* __restrict__ W0, const float4* __restrict__ W1,
                        uint2* __restrict__ hvb2, float* __restrict__ part,
                        const float* __restrict__ W, unsigned short* __restrict__ wf,
                        const int* __restrict__ edst, int* __restrict__ deg) {
    int tid = threadIdx.x;
    if (blockIdx.x >= EMB_BLK + WF_BLK) {
        int e = (blockIdx.x - EMB_BLK - WF_BLK) * 256 + tid;
        if (e < N_EDGESC) atomicAdd(&deg[edst[e]], 1);
        return;
    }
    if (blockIdx.x >= EMB_BLK) {
        int i = (blockIdx.x - EMB_BLK) * 256 + tid;
        if (i < LAYERS * 16384) {
            int j = i & 7;
            int lane = (i >> 3) & 63;
            int nt = (i >> 9) & 7;
            int ks = (i >> 12) & 3;
            int l = i >> 14;
            int k = ks * 32 + (lane >> 4) * 8 + j;
            int n = nt * 16 + (lane & 15);
            wf[i] = f2bf(W[(size_t)l * HID * HID + k * HID + n]);
        }
        return;
    }
    __shared__ float sh[1024], sh2[1024];
    int i = blockIdx.x * 256 + tid;
    int v = i >> 5, c4 = i & 31;
    float4 a = W0[f0[v] * 32 + c4];
    float4 b = W1[f1[v] * 32 + c4];
    float4 o = make_float4(a.x + b.x, a.y + b.y, a.z + b.z, a.w + b.w);
    uint2 ob;
    ob.x = (unsigned)f2bf(o.x) | ((unsigned)f2bf(o.y) << 16);
    ob.y = (unsigned)f2bf(o.z) | ((unsigned)f2bf(o.w) << 16);
    hvb2[i] = ob;
    sh[tid * 4 + 0] = o.x; sh2[tid * 4 + 0] = o.x * o.x;
    sh[tid * 4 + 1] = o.y; sh2[tid * 4 + 1] = o.y * o.y;
    sh[tid * 4 + 2] = o.z; sh2[tid * 4 + 2] = o.z * o.z;
    sh[tid * 4 + 3] = o.w; sh2[tid * 4 + 3] = o.w * o.w;
    __syncthreads();
    if (tid < 128) {
        int c4i = tid >> 2, j = tid & 3;
        float s = 0.f, s2 = 0.f;
#pragma unroll
        for (int r = 0; r < 8; r++) {
            s += sh[(r * 32 + c4i) * 4 + j];
            s2 += sh2[(r * 32 + c4i) * 4 + j];
        }
        part[(size_t)blockIdx.x * 256 + tid] = s;
        part[(size_t)blockIdx.x * 256 + 128 + tid] = s2;
    }
}

// layer-0 partial reduce -> gsums[0] (zeroed once up front)
__global__ void k_bn_reduce2(const float* __restrict__ part, int nparts,
                             float* __restrict__ gsum) {
    int t = threadIdx.x;
    int rows = (nparts + BNR_BLK - 1) / BNR_BLK;
    int r0 = blockIdx.x * rows;
    int r1 = min(r0 + rows, nparts);
    float s = 0.f;
    for (int p = r0; p < r1; p++) s += part[(size_t)p * 256 + t];
    atomicAdd(&gsum[t], s);
}

// ---------------- FUSED: BN-inline agg -> LDS -> MFMA GEMM -------------------
// Block = 64 nodes, 512 threads. Gathers from hin (pre-BN bf16, ping), applies
// BN+ReLU inline per gathered row; writes post-skip rows to hout (pong).
// Epilogue: layers 0..1 -> next-layer BN stats; layer 2 -> per-graph pooling.
__global__ __launch_bounds__(512) void k_aggemm(
    const unsigned* __restrict__ hin, unsigned short* __restrict__ hout,
    const int* __restrict__ row_ptr, const int* __restrict__ csr_pack,
    const float* __restrict__ e0, const float* __restrict__ e1,
    const float* __restrict__ beta_p, const unsigned short* __restrict__ wf,
    const float* __restrict__ b, const float* __restrict__ gsum,
    const float* __restrict__ gamma, const float* __restrict__ betab,
    float* __restrict__ gsum_next, float* __restrict__ hg) {
    __shared__ float2 sh_et[18 * 64];      // 9216 B
    __shared__ unsigned x_tile[64 * 64];   // 16384 B: [row][rot col]
    __shared__ float shs[512], shs2[512];  // 4096 B
    int tid = threadIdx.x;
    for (int i = tid; i < 18 * 64; i += 512) {
        int f = i >> 6, ln = i & 63;
        int a = f / 3, bb = f - 3 * a;
        float2 ea = *(const float2*)(e0 + a * HID + 2 * ln);
        float2 eb = *(const float2*)(e1 + bb * HID + 2 * ln);
        sh_et[i] = make_float2(ea.x + eb.x, ea.y + eb.y);
    }
    int w = tid >> 6, lane = tid & 63;
    int m0 = blockIdx.x * 64;
    const float bl2 = (*beta_p) * LOG2E;
    // per-lane BN coefficients for channels (2*lane, 2*lane+1)
    const float invN = 1.f / (float)N_NODESC;
    int cch = lane * 2;
    float mu0 = gsum[cch] * invN, mu1 = gsum[cch + 1] * invN;
    float var0 = gsum[128 + cch] * invN - mu0 * mu0;
    float var1 = gsum[129 + cch] * invN - mu1 * mu1;
    float sc0 = gamma[cch] * rsqrtf(var0 + BN_EPS);
    float sc1 = gamma[cch + 1] * rsqrtf(var1 + BN_EPS);
    float sf0 = betab[cch] - mu0 * sc0;
    float sf1 = betab[cch + 1] - mu1 * sc1;
    __syncthreads();

    const char* hinc = (const char*)hin;
    const char* etc = (const char*)sh_et;
    unsigned lane4 = (unsigned)lane * 4;
    unsigned lane8 = (unsigned)lane * 8;

#define AGG_BODY(J)                                                         \
    {                                                                       \
        int pack = __shfl(pk, (J), 64);                                     \
        unsigned u = *(const unsigned*)(hinc +                              \
                        ((((unsigned)pack) & 0xFFFFFF00u) + lane4));        \
        float2 t = *(const float2*)(etc +                                   \
                        (((((unsigned)pack) & 0xFFu) << 6) + lane8));       \
        float a0 = fmaxf(fmaf(bf_lo(u), sc0, sf0), 0.f);                    \
        float a1 = fmaxf(fmaf(bf_hi(u), sc1, sf1), 0.f);                    \
        float r0 = fmaxf(a0 + t.x, 0.f);                                    \
        float r1 = fmaxf(a1 + t.y, 0.f);                                    \
        float w0 = exp2f(r0 * bl2);                                         \
        float w1 = exp2f(r1 * bl2);                                         \
        d0 += w0; d1 += w1;                                                 \
        n0 = fmaf(r0, w0, n0); n1 = fmaf(r1, w1, n1);                       \
    }

    // ---- phase 1: aggregation, 8 nodes per wave ----
    for (int i = 0; i < 8; i++) {
        int row = w * 8 + i;
        int v = m0 + row;
        int vc = min(v, N_NODESC - 1);
        unsigned su = hin[(size_t)vc * 64 + lane];
        float h10 = fmaxf(fmaf(bf_lo(su), sc0, sf0), 0.f);
        float h11 = fmaxf(fmaf(bf_hi(su), sc1, sf1), 0.f);
        int p0 = row_ptr[vc];
        int deg = (v < N_NODESC) ? (row_ptr[vc + 1] - p0) : 0;
        float n0 = 0.f, n1 = 0.f, d0 = 0.f, d1 = 0.f;
        for (int base = 0; base < deg; base += 64) {
            int idx = base + lane;
            int pk = (idx < deg) ? csr_pack[p0 + idx] : 0;
            int jn = min(64, deg - base);
            int j = 0;
            for (; j + 2 <= jn; j += 2) {
                AGG_BODY(j)
                AGG_BODY(j + 1)
            }
            if (j < jn) AGG_BODY(j)
        }
        float ox = h10 + (deg ? __fdividef(n0, d0) + GEN_EPS : 0.f);
        float oy = h11 + (deg ? __fdividef(n1, d1) + GEN_EPS : 0.f);
        x_tile[row * 64 + ((lane + row * 4) & 63)] =
            (unsigned)f2bf(ox) | ((unsigned)f2bf(oy) << 16);
    }
#undef AGG_BODY
    __syncthreads();

    // ---- phase 2: MFMA ----
    int rw = w & 3, chh = w >> 2;
    int mrow = lane & 15, grp = lane >> 4;
    int rbase = rw * 16 + mrow;
    bf16x8 af[4];
#pragma unroll
    for (int ks = 0; ks < 4; ks++) {
        int col = ks * 16 + grp * 4;
        int colr = (col + rbase * 4) & 63;
        af[ks] = *(const bf16x8*)&x_tile[rbase * 64 + colr];
    }
    f32x4 acc[4];
#pragma unroll
    for (int nt = 0; nt < 4; nt++) acc[nt] = (f32x4){0.f, 0.f, 0.f, 0.f};
#pragma unroll
    for (int nt = 0; nt < 4; nt++) {
        int ntg = chh * 4 + nt;
#pragma unroll
        for (int ks = 0; ks < 4; ks++) {
            bf16x8 bfr = *(const bf16x8*)(wf +
                (size_t)((ks * 8 + ntg) * 64 + lane) * 8);
            acc[nt] = __builtin_amdgcn_mfma_f32_16x16x32_bf16(
                af[ks], bfr, acc[nt], 0, 0, 0);
        }
    }
    // epilogue: bias + skip (hin -> hout) + stats or pooling
    const unsigned short* hin_s = (const unsigned short*)hin;
    int gA = m0 / 3125;
    int boundary = (gA + 1) * 3125;
#pragma unroll
    for (int nt = 0; nt < 4; nt++) {
        int col = chh * 64 + nt * 16 + mrow;
        float bias = b[col];
        float s = 0.f, s2 = 0.f;
#pragma unroll
        for (int r = 0; r < 4; r++) {
            int v = m0 + rw * 16 + grp * 4 + r;
            if (v < N_NODESC) {
                size_t idx = (size_t)v * HID + col;
                float o = acc[nt][r] + bias + bfs(hin_s[idx]);
                hout[idx] = f2bf(o);
                if (hg) {                 // last layer: pool by graph
                    if (v < boundary) s += o; else s2 += o;
                } else {                  // stats for next layer BN
                    s += o; s2 += o * o;
                }
            }
        }
        s  += __shfl_xor(s, 16, 64);  s  += __shfl_xor(s, 32, 64);
        s2 += __shfl_xor(s2, 16, 64); s2 += __shfl_xor(s2, 32, 64);
        if (lane < 16) { shs[rw * 128 + col] = s; shs2[rw * 128 + col] = s2; }
    }
    __syncthreads();
    if (hg) {
        int gB = min(m0 + 63, N_NODESC - 1) / 3125;
        if (tid < 128) {
            atomicAdd(&hg[gA * 128 + tid],
                shs[tid] + shs[128 + tid] + shs[256 + tid] + shs[384 + tid]);
        } else if (tid < 256 && gB != gA) {
            int c = tid - 128;
            atomicAdd(&hg[gB * 128 + c],
                shs2[c] + shs2[128 + c] + shs2[256 + c] + shs2[384 + c]);
        }
    } else if (gsum_next) {
        if (tid < 128) {
            atomicAdd(&gsum_next[tid],
                shs[tid] + shs[128 + tid] + shs[256 + tid] + shs[384 + tid]);
        } else if (tid < 256) {
            int c = tid - 128;
            atomicAdd(&gsum_next[tid],
                shs2[c] + shs2[128 + c] + shs2[256 + c] + shs2[384 + c]);
        }
    }
}

// ---------------- output linear (hg already pooled via atomics) -------------
__global__ void k_finish(const float* __restrict__ hg, const float* __restrict__ Wo,
                         const float* __restrict__ bo, float* __restrict__ out) {
    int t = threadIdx.x;
    if (t >= N_GRAPHSC * OUT_DIM) return;
    int g = t / OUT_DIM, o = t % OUT_DIM;
    const float inv = (float)N_GRAPHSC / (float)N_NODESC;
    float acc = bo[o];
    for (int k = 0; k < HID; k++)
        acc += hg[g * HID + k] * inv * Wo[k * OUT_DIM + o];
    out[t] = acc;
}

extern "C" void kernel_launch(void* const* d_in, const int* in_sizes, int n_in,
                              void* d_out, int out_size, void* d_ws, size_t ws_size,
                              hipStream_t stream) {
    const int* node_feat0 = (const int*)d_in[0];
    const int* node_feat1 = (const int*)d_in[1];
    const int* edge_feat0 = (const int*)d_in[2];
    const int* edge_feat1 = (const int*)d_in[3];
    const int* edge_src   = (const int*)d_in[4];
    const int* edge_dst   = (const int*)d_in[5];
    const float* W_node0   = (const float*)d_in[8];
    const float* W_node1   = (const float*)d_in[9];
    const float* edge_emb0 = (const float*)d_in[10];
    const float* edge_emb1 = (const float*)d_in[11];
    const float* beta      = (const float*)d_in[12];
    const float* mlp_W     = (const float*)d_in[13];
    const float* mlp_b     = (const float*)d_in[14];
    const float* bn_gamma  = (const float*)d_in[15];
    const float* bn_beta   = (const float*)d_in[16];
    const float* W_out     = (const float*)d_in[17];
    const float* b_out     = (const float*)d_in[18];
    float* out = (float*)d_out;

    char* ws = (char*)d_ws;
    size_t off = 0;
    auto alloc = [&](size_t bytes) -> void* {
        void* p = ws + off;
        off += (bytes + 255) & ~(size_t)255;
        return p;
    };
    unsigned short* hvA = (unsigned short*)alloc((size_t)N_NODESC * HID * 2);
    unsigned short* hvB = (unsigned short*)alloc((size_t)N_NODESC * HID * 2);
    float* gsums   = (float*)alloc(LAYERS * 256 * 4);              // 3072 B
    float* hg      = (float*)alloc(N_GRAPHSC * HID * 4);           // contiguous after
    float* bnpart  = (float*)alloc((size_t)EMB_BLK * 256 * 4);
    unsigned short* wfrag = (unsigned short*)alloc((size_t)LAYERS * 16384 * 2);
    int* row_ptr   = (int*)alloc((N_NODESC + 1) * 4);
    int* cursor    = (int*)alloc(N_NODESC * 4);
    int* deg       = (int*)alloc(N_NODESC * 4);
    int* part      = (int*)alloc(SCAN_BLK * 4);
    int* bofs      = (int*)alloc(SCAN_BLK * 4);
    int* csr_pack  = (int*)alloc((size_t)N_EDGESC * 4);

    // ---- zero: deg, and gsums+hg (contiguous: 3072 + 8192 bytes) ----
    hipMemsetAsync(deg, 0, N_NODESC * 4, stream);
    hipMemsetAsync(gsums, 0, LAYERS * 256 * 4 + N_GRAPHSC * HID * 4, stream);

    // ---- embed (+layer-0 BN partials) + wfrag + degree count, one grid ----
    k_embed<<<EMB_BLK + WF_BLK + CNT_BLK, 256, 0, stream>>>(
        node_feat0, node_feat1, (const float4*)W_node0, (const float4*)W_node1,
        (uint2*)hvA, bnpart, mlp_W, wfrag, edge_dst, deg);

    // ---- CSR (edge_dst is layer-invariant) ----
    k_blocksum<<<SCAN_BLK, 256, 0, stream>>>(deg, part);
    k_scanpart<<<1, 256, 0, stream>>>(part, bofs);
    k_rowptr<<<SCAN_BLK, 256, 0, stream>>>(deg, bofs, row_ptr, cursor);
    k_scatter<<<(N_EDGESC + 255) / 256, 256, 0, stream>>>(
        edge_dst, edge_src, edge_feat0, edge_feat1, cursor, csr_pack);

    // ---- layer-0 BN stats reduce ----
    k_bn_reduce2<<<BNR_BLK, 256, 0, stream>>>(bnpart, EMB_BLK, gsums);

    // ---- layers (ping-pong hvA/hvB) ----
    unsigned short* hin = hvA;
    unsigned short* hout = hvB;
    for (int l = 0; l < LAYERS; l++) {
        float* gsum = gsums + l * 256;
        float* gnext = (l + 1 < LAYERS) ? gsums + (l + 1) * 256 : nullptr;
        float* hgp = (l == LAYERS - 1) ? hg : nullptr;
        k_aggemm<<<GEMM_BLK, 512, 0, stream>>>(
            (const unsigned*)hin, hout, row_ptr, csr_pack,
            edge_emb0 + (size_t)l * 6 * HID, edge_emb1 + (size_t)l * 3 * HID,
            beta + l, wfrag + (size_t)l * 16384, mlp_b + l * HID,
            gsum, bn_gamma + l * HID, bn_beta + l * HID, gnext, hgp);
        unsigned short* tmp = hin; hin = hout; hout = tmp;
    }

    // ---- output ----
    k_finish<<<1, 256, 0, stream>>>(hg, W_out, b_out, out);
}